// Round 8
// baseline (324.843 us; speedup 1.0000x reference)
//
#include <hip/hip_runtime.h>

#define B_ 4
#define N_ 4096
#define DIM_ 512
#define H_ 8
#define DH_ 64
#define F_ 256
#define CS_ 128
#define M_ (B_*N_)         // 16384
#define NCHUNK_ 1024

typedef __attribute__((ext_vector_type(8))) short bf16x8;
typedef __attribute__((ext_vector_type(4))) float f32x4;

__device__ __forceinline__ unsigned short f2bf(float x){
  unsigned int u = __float_as_uint(x);
  u += 0x7fffu + ((u >> 16) & 1u);          // RNE
  return (unsigned short)(u >> 16);
}
__device__ __forceinline__ float bf2f(unsigned short s){
  return __uint_as_float(((unsigned int)s) << 16);
}
__device__ __forceinline__ unsigned pack2(float a, float b){
  return (unsigned)f2bf(a) | ((unsigned)f2bf(b) << 16);
}
__device__ __forceinline__ void gl2lds16(const unsigned short* g, unsigned short* l) {
  __builtin_amdgcn_global_load_lds((const __attribute__((address_space(1))) unsigned int*)g,
                                   (__attribute__((address_space(3))) unsigned int*)l,
                                   16, 0, 0);
}

// fp32 -> bf16 hi + lo
__global__ __launch_bounds__(256)
void split_kernel(const float* __restrict__ src, unsigned short* __restrict__ hi,
                  unsigned short* __restrict__ lo, int n4)
{
  int idx = blockIdx.x * 256 + threadIdx.x;
  if (idx >= n4) return;
  float4 v = ((const float4*)src)[idx];
  unsigned short h0 = f2bf(v.x), h1 = f2bf(v.y), h2 = f2bf(v.z), h3 = f2bf(v.w);
  unsigned short e0 = f2bf(v.x - bf2f(h0)), e1 = f2bf(v.y - bf2f(h1));
  unsigned short e2 = f2bf(v.z - bf2f(h2)), e3 = f2bf(v.w - bf2f(h3));
  uint2 hv, lv;
  hv.x = (unsigned)h0 | ((unsigned)h1 << 16); hv.y = (unsigned)h2 | ((unsigned)h3 << 16);
  lv.x = (unsigned)e0 | ((unsigned)e1 << 16); lv.y = (unsigned)e2 | ((unsigned)e3 << 16);
  ((uint2*)hi)[idx] = hv;
  ((uint2*)lo)[idx] = lv;
}

// Combined feature weights: Wqp_h = (proj*0.125) @ Wq_h,  Wkp_h = proj @ Wk_h  (bf16 out).
// grid (8 h, 2 which, 8 z): z = ftile(4)*2 + jtile(2). Block computes 64 f x 256 j, K=64.
__global__ __launch_bounds__(256, 2)
void wcomb_kernel(const float* __restrict__ proj, const float* __restrict__ w_qkv,
                  unsigned short* __restrict__ wqp, unsigned short* __restrict__ wkp)
{
  __shared__ float projL[64 * 64];    // [d][f_local]
  __shared__ float wL[64 * 256];      // [d][j_local]
  const int h = blockIdx.x, which = blockIdx.y, z = blockIdx.z;
  const int fbase = (z >> 1) * 64, jbase = (z & 1) * 256;
  const int tid = threadIdx.x;
  const float scale = which ? 1.0f : 0.125f;
#pragma unroll
  for (int i = 0; i < 16; ++i) {
    int e = tid + i * 256;                 // 0..4095
    int fl = e >> 6, d = e & 63;
    projL[d * 64 + fl] = proj[(size_t)(fbase + fl) * 64 + d] * scale;
  }
  const float* wsrc = w_qkv + (size_t)(which * 512 + h * 64) * 512 + jbase;
#pragma unroll
  for (int i = 0; i < 16; ++i) {
    int e = tid + i * 256;                 // float4 idx
    int d = e >> 6, j4 = e & 63;
    *(float4*)&wL[d * 256 + j4 * 4] = *(const float4*)(wsrc + (size_t)d * 512 + j4 * 4);
  }
  __syncthreads();
  const int tf = tid & 15, tj = tid >> 4;
  const int f0 = tf * 4, j0 = tj * 16;
  float acc[4][16];
#pragma unroll
  for (int i = 0; i < 4; ++i)
#pragma unroll
    for (int j = 0; j < 16; ++j) acc[i][j] = 0.f;
  for (int d = 0; d < 64; ++d) {
    float p0 = projL[d*64 + f0], p1 = projL[d*64 + f0 + 1];
    float p2 = projL[d*64 + f0 + 2], p3 = projL[d*64 + f0 + 3];
    float4 w0 = *(const float4*)&wL[d*256 + j0];
    float4 w1 = *(const float4*)&wL[d*256 + j0 + 4];
    float4 w2 = *(const float4*)&wL[d*256 + j0 + 8];
    float4 w3 = *(const float4*)&wL[d*256 + j0 + 12];
    float wv[16] = {w0.x,w0.y,w0.z,w0.w, w1.x,w1.y,w1.z,w1.w,
                    w2.x,w2.y,w2.z,w2.w, w3.x,w3.y,w3.z,w3.w};
    float pv[4] = {p0,p1,p2,p3};
#pragma unroll
    for (int i = 0; i < 4; ++i)
#pragma unroll
      for (int j = 0; j < 16; ++j) acc[i][j] = fmaf(pv[i], wv[j], acc[i][j]);
  }
  unsigned short* dst = (which ? wkp : wqp) + (size_t)h * 256 * 512;
#pragma unroll
  for (int i = 0; i < 4; ++i) {
    int f = fbase + f0 + i;
#pragma unroll
    for (int c = 0; c < 4; ++c) {
      uint2 w;
      w.x = pack2(acc[i][c*4+0], acc[i][c*4+1]);
      w.y = pack2(acc[i][c*4+2], acc[i][c*4+3]);
      *(uint2*)(dst + (size_t)f * 512 + jbase + j0 + c * 4) = w;
    }
  }
}

// C[m][n] = sum_k A[m][k]*B[n][k]. SPLIT: 3-term bf16 emu of fp32.
// OUT: 0=f32(+bias), 2=v-transpose hi/lo split into vth/vtl (swizzled chunk layout).
template<int SPLIT, int OUT>
__global__ __launch_bounds__(256, 2)
void mfma_gemm_nt(const unsigned short* __restrict__ Ahi, const unsigned short* __restrict__ Alo,
                  const unsigned short* __restrict__ Bhi, const unsigned short* __restrict__ Blo,
                  void* __restrict__ Cm, const float* __restrict__ bias, int K, int ldc,
                  unsigned short* __restrict__ vth, unsigned short* __restrict__ vtl)
{
  __shared__ __align__(16) unsigned short sAhi[4096];
  __shared__ __align__(16) unsigned short sBhi[4096];
  __shared__ __align__(16) unsigned short sAlo[4096];
  __shared__ __align__(16) unsigned short sBlo[4096];
  const int tid = threadIdx.x, lane = tid & 63, wave = tid >> 6;
  const int bm = blockIdx.y * 128, bn = blockIdx.x * 128;
  const int srow0 = wave * 32 + (lane >> 2);
  const int srow1 = srow0 + 16;
  const int slot = lane & 3;
  const int g0 = slot ^ ((srow0 >> 1) & 3);
  const int g1 = slot ^ ((srow1 >> 1) & 3);
  const size_t aOff0 = (size_t)(bm + srow0) * K + g0 * 8;
  const size_t aOff1 = (size_t)(bm + srow1) * K + g1 * 8;
  const size_t bOff0 = (size_t)(bn + srow0) * K + g0 * 8;
  const size_t bOff1 = (size_t)(bn + srow1) * K + g1 * 8;
  const int l0 = wave * 1024, l1 = wave * 1024 + 512;
  const int fr = lane & 15, quad = lane >> 4;
  const int wr = (wave >> 1) * 64, wc = (wave & 1) * 64;
  int offA[4], offB[4];
#pragma unroll
  for (int i = 0; i < 4; ++i) {
    int ra = wr + i * 16 + fr;  offA[i] = ra * 32 + (quad ^ ((ra >> 1) & 3)) * 8;
    int rb = wc + i * 16 + fr;  offB[i] = rb * 32 + (quad ^ ((rb >> 1) & 3)) * 8;
  }
  f32x4 acc[4][4];
#pragma unroll
  for (int i = 0; i < 4; ++i)
#pragma unroll
    for (int j = 0; j < 4; ++j) acc[i][j] = {0.f, 0.f, 0.f, 0.f};

  for (int k0 = 0; k0 < K; k0 += 32) {
    gl2lds16(Ahi + aOff0 + k0, &sAhi[l0]);
    gl2lds16(Ahi + aOff1 + k0, &sAhi[l1]);
    gl2lds16(Bhi + bOff0 + k0, &sBhi[l0]);
    gl2lds16(Bhi + bOff1 + k0, &sBhi[l1]);
    if (SPLIT) {
      gl2lds16(Alo + aOff0 + k0, &sAlo[l0]);
      gl2lds16(Alo + aOff1 + k0, &sAlo[l1]);
      gl2lds16(Blo + bOff0 + k0, &sBlo[l0]);
      gl2lds16(Blo + bOff1 + k0, &sBlo[l1]);
    }
    __syncthreads();
    bf16x8 ah[4], bh[4], al[4], bl[4];
#pragma unroll
    for (int i = 0; i < 4; ++i) {
      ah[i] = *(const bf16x8*)&sAhi[offA[i]];
      bh[i] = *(const bf16x8*)&sBhi[offB[i]];
      if (SPLIT) {
        al[i] = *(const bf16x8*)&sAlo[offA[i]];
        bl[i] = *(const bf16x8*)&sBlo[offB[i]];
      }
    }
#pragma unroll
    for (int i = 0; i < 4; ++i)
#pragma unroll
      for (int j = 0; j < 4; ++j) {
        acc[i][j] = __builtin_amdgcn_mfma_f32_16x16x32_bf16(ah[i], bh[j], acc[i][j], 0, 0, 0);
        if (SPLIT) {
          acc[i][j] = __builtin_amdgcn_mfma_f32_16x16x32_bf16(ah[i], bl[j], acc[i][j], 0, 0, 0);
          acc[i][j] = __builtin_amdgcn_mfma_f32_16x16x32_bf16(al[i], bh[j], acc[i][j], 0, 0, 0);
        }
      }
    __syncthreads();
  }
#pragma unroll
  for (int j = 0; j < 4; ++j) {
    int col = bn + wc + j * 16 + fr;
    float bv = (OUT == 0 && bias) ? bias[col] : 0.f;
#pragma unroll
    for (int i = 0; i < 4; ++i) {
      int row0 = bm + wr + i * 16 + quad * 4;
      if (OUT == 0) {
        float* cp = (float*)Cm + (size_t)row0 * ldc + col;
#pragma unroll
        for (int r = 0; r < 4; ++r) cp[(size_t)r * ldc] = acc[i][j][r] + bv;
      } else {
        int hh = col >> 6, d = col & 63;
        int bb = row0 >> 12, cc2 = (row0 >> 7) & 31, s = row0 & 127;
        int ck = bb * 256 + hh * 32 + cc2;
        size_t ad = (size_t)ck * 8192 + d * 128 + (((s >> 3) ^ (d & 15)) << 3) + (s & 7);
        float v0 = acc[i][j][0], v1 = acc[i][j][1], v2 = acc[i][j][2], v3 = acc[i][j][3];
        unsigned short h0 = f2bf(v0), h1 = f2bf(v1), h2 = f2bf(v2), h3 = f2bf(v3);
        uint2 hv, lv;
        hv.x = (unsigned)h0 | ((unsigned)h1 << 16);
        hv.y = (unsigned)h2 | ((unsigned)h3 << 16);
        lv.x = pack2(v0 - bf2f(h0), v1 - bf2f(h1));
        lv.y = pack2(v2 - bf2f(h2), v3 - bf2f(h3));
        *(uint2*)(vth + ad) = hv;
        *(uint2*)(vtl + ad) = lv;
      }
    }
  }
}

// feat_k: per chunk, C[s 128][f 256] = x_hi-tile @ Wkp_h^T (K=512, BK=64 LDS staging),
// rowmax/exp, ksum -> global, kpT [f][128 s] swz -> LDS bounce -> global (coalesced).
__global__ __launch_bounds__(256, 2)
void feat_k(const unsigned short* __restrict__ x_hi, const unsigned short* __restrict__ wkp,
            unsigned short* __restrict__ kpT_g, float* __restrict__ ksum_g)
{
  __shared__ __align__(16) char smem[69632];
  unsigned short* SA = (unsigned short*)smem;            // [128 s][64 k swz8]  16 KB
  unsigned short* SB = SA + 8192;                        // [256 f][64 k swz8]  32 KB
  unsigned short* KP = SA;                               // bounce 64 KB after loop
  float* KSP = (float*)(smem + 65536);                   // [4][256]
  const int tid = threadIdx.x, lane = tid & 63, wave = tid >> 6;
  const int fr = lane & 15, quad = lane >> 4;
  const int chunk = blockIdx.x;
  const int b = chunk >> 8, h = (chunk >> 5) & 7, cc = chunk & 31;
  const int mbase = b * N_ + cc * CS_;
  const unsigned short* wk = wkp + (size_t)h * 256 * 512;

  f32x4 ka[2][16];
#pragma unroll
  for (int nt = 0; nt < 16; ++nt) { ka[0][nt] = {0,0,0,0}; ka[1][nt] = {0,0,0,0}; }

  for (int kit = 0; kit < 8; ++kit) {
    int k0 = kit * 64;
#pragma unroll
    for (int i = 0; i < 4; ++i) {
      int u = (wave * 4 + i) * 64 + lane;
      int s = u >> 3, jg = u & 7;
      gl2lds16(x_hi + (size_t)(mbase + s) * 512 + k0 + ((jg ^ (s & 7)) << 3),
               SA + (size_t)(wave * 4 + i) * 512);
    }
#pragma unroll
    for (int i = 0; i < 8; ++i) {
      int u = (wave * 8 + i) * 64 + lane;
      int f = u >> 3, jg = u & 7;
      gl2lds16(wk + (size_t)f * 512 + k0 + ((jg ^ (f & 7)) << 3),
               SB + (size_t)(wave * 8 + i) * 512);
    }
    __syncthreads();
#pragma unroll
    for (int kin = 0; kin < 2; ++kin) {
      int g8 = kin * 4 + quad;
      bf16x8 a[2];
#pragma unroll
      for (int mt = 0; mt < 2; ++mt) {
        int s = wave * 32 + mt * 16 + fr;
        a[mt] = *(const bf16x8*)(SA + s * 64 + ((g8 ^ (s & 7)) << 3));
      }
#pragma unroll
      for (int nt = 0; nt < 16; ++nt) {
        int f = nt * 16 + fr;
        bf16x8 bb = *(const bf16x8*)(SB + f * 64 + ((g8 ^ (f & 7)) << 3));
        ka[0][nt] = __builtin_amdgcn_mfma_f32_16x16x32_bf16(a[0], bb, ka[0][nt], 0, 0, 0);
        ka[1][nt] = __builtin_amdgcn_mfma_f32_16x16x32_bf16(a[1], bb, ka[1][nt], 0, 0, 0);
      }
    }
    __syncthreads();
  }
  // rowmax + exp (per s)
#pragma unroll
  for (int mt = 0; mt < 2; ++mt)
#pragma unroll
    for (int r = 0; r < 4; ++r) {
      float m = ka[mt][0][r];
#pragma unroll
      for (int nt = 1; nt < 16; ++nt) m = fmaxf(m, ka[mt][nt][r]);
      m = fmaxf(m, __shfl_xor(m, 1, 16));
      m = fmaxf(m, __shfl_xor(m, 2, 16));
      m = fmaxf(m, __shfl_xor(m, 4, 16));
      m = fmaxf(m, __shfl_xor(m, 8, 16));
#pragma unroll
      for (int nt = 0; nt < 16; ++nt) ka[mt][nt][r] = __expf(ka[mt][nt][r] - m);
    }
  // ksum partials + kpT scatter into LDS
#pragma unroll
  for (int nt = 0; nt < 16; ++nt) {
    float sm = 0.f;
#pragma unroll
    for (int mt = 0; mt < 2; ++mt)
#pragma unroll
      for (int r = 0; r < 4; ++r) sm += ka[mt][nt][r];
    sm += __shfl_xor(sm, 16, 64);
    sm += __shfl_xor(sm, 32, 64);
    if (quad == 0) KSP[wave * 256 + nt * 16 + fr] = sm;
  }
#pragma unroll
  for (int nt = 0; nt < 16; ++nt) {
    int f = nt * 16 + fr;
#pragma unroll
    for (int mt = 0; mt < 2; ++mt) {
      int g = wave * 4 + mt * 2 + (quad >> 1);
      uint2 w;
      w.x = pack2(ka[mt][nt][0], ka[mt][nt][1]);
      w.y = pack2(ka[mt][nt][2], ka[mt][nt][3]);
      *(uint2*)(KP + f * 128 + ((g ^ (f & 15)) << 3) + (quad & 1) * 4) = w;
    }
  }
  __syncthreads();
  ksum_g[(size_t)chunk * 256 + tid] =
      KSP[tid] + KSP[256 + tid] + KSP[512 + tid] + KSP[768 + tid];
#pragma unroll
  for (int i = 0; i < 16; ++i) {
    int idx = i * 256 + tid;
    *(float4*)(kpT_g + (size_t)chunk * 32768 + idx * 8) = *(const float4*)(KP + idx * 8);
  }
}

// feat_q: per chunk, C[f 256][s 128] = Wqp_h @ x-tile^T, colmax over f, exp,
// D = qp.ksum (fp32) -> di_g, qp [s][256 f] swz -> LDS bounce -> global.
__global__ __launch_bounds__(256, 2)
void feat_q(const unsigned short* __restrict__ x_hi, const unsigned short* __restrict__ wqp,
            const float* __restrict__ ksum_g, float* __restrict__ di_g,
            unsigned short* __restrict__ qp_g)
{
  __shared__ __align__(16) char smem[66560];
  unsigned short* SA = (unsigned short*)smem;            // x tile 16 KB
  unsigned short* SB = SA + 8192;                        // Wqp 32 KB
  unsigned short* QP = SA;                               // bounce 64 KB
  float* KS = (float*)(smem + 65536);                    // [256]
  const int tid = threadIdx.x, lane = tid & 63, wave = tid >> 6;
  const int fr = lane & 15, quad = lane >> 4;
  const int chunk = blockIdx.x;
  const int b = chunk >> 8, h = (chunk >> 5) & 7, cc = chunk & 31;
  const int mbase = b * N_ + cc * CS_;
  const unsigned short* wq = wqp + (size_t)h * 256 * 512;

  KS[tid] = ksum_g[(size_t)chunk * 256 + tid];

  f32x4 qa[16][2];
#pragma unroll
  for (int mt = 0; mt < 16; ++mt) { qa[mt][0] = {0,0,0,0}; qa[mt][1] = {0,0,0,0}; }

  for (int kit = 0; kit < 8; ++kit) {
    int k0 = kit * 64;
#pragma unroll
    for (int i = 0; i < 4; ++i) {
      int u = (wave * 4 + i) * 64 + lane;
      int s = u >> 3, jg = u & 7;
      gl2lds16(x_hi + (size_t)(mbase + s) * 512 + k0 + ((jg ^ (s & 7)) << 3),
               SA + (size_t)(wave * 4 + i) * 512);
    }
#pragma unroll
    for (int i = 0; i < 8; ++i) {
      int u = (wave * 8 + i) * 64 + lane;
      int f = u >> 3, jg = u & 7;
      gl2lds16(wq + (size_t)f * 512 + k0 + ((jg ^ (f & 7)) << 3),
               SB + (size_t)(wave * 8 + i) * 512);
    }
    __syncthreads();
#pragma unroll
    for (int kin = 0; kin < 2; ++kin) {
      int g8 = kin * 4 + quad;
      bf16x8 bx[2];
#pragma unroll
      for (int nt = 0; nt < 2; ++nt) {
        int s = wave * 32 + nt * 16 + fr;
        bx[nt] = *(const bf16x8*)(SA + s * 64 + ((g8 ^ (s & 7)) << 3));
      }
#pragma unroll
      for (int mt = 0; mt < 16; ++mt) {
        int f = mt * 16 + fr;
        bf16x8 af = *(const bf16x8*)(SB + f * 64 + ((g8 ^ (f & 7)) << 3));
        qa[mt][0] = __builtin_amdgcn_mfma_f32_16x16x32_bf16(af, bx[0], qa[mt][0], 0, 0, 0);
        qa[mt][1] = __builtin_amdgcn_mfma_f32_16x16x32_bf16(af, bx[1], qa[mt][1], 0, 0, 0);
      }
    }
    __syncthreads();
  }
  // per-token (col) max over f, exp, D
#pragma unroll
  for (int nt = 0; nt < 2; ++nt) {
    float m = -1e30f;
#pragma unroll
    for (int mt = 0; mt < 16; ++mt)
#pragma unroll
      for (int r = 0; r < 4; ++r) m = fmaxf(m, qa[mt][nt][r]);
    m = fmaxf(m, __shfl_xor(m, 16, 64));
    m = fmaxf(m, __shfl_xor(m, 32, 64));
#pragma unroll
    for (int mt = 0; mt < 16; ++mt)
#pragma unroll
      for (int r = 0; r < 4; ++r) qa[mt][nt][r] = __expf(qa[mt][nt][r] - m);
    float dp = 0.f;
#pragma unroll
    for (int mt = 0; mt < 16; ++mt) {
      f32x4 k4 = *(const f32x4*)(KS + mt * 16 + quad * 4);
#pragma unroll
      for (int r = 0; r < 4; ++r) dp = fmaf(qa[mt][nt][r], k4[r], dp);
    }
    dp += __shfl_xor(dp, 16, 64);
    dp += __shfl_xor(dp, 32, 64);
    if (quad == 0) {
      int s = wave * 32 + nt * 16 + fr;
      di_g[(size_t)chunk * 128 + s] = 1.f / (dp + 1e-4f);
    }
  }
  // qp scatter -> LDS bounce
#pragma unroll
  for (int nt = 0; nt < 2; ++nt) {
    int s = wave * 32 + nt * 16 + fr;
#pragma unroll
    for (int mt = 0; mt < 16; ++mt) {
      int g = mt * 2 + (quad >> 1);
      uint2 w;
      w.x = pack2(qa[mt][nt][0], qa[mt][nt][1]);
      w.y = pack2(qa[mt][nt][2], qa[mt][nt][3]);
      *(uint2*)(QP + s * 256 + ((g ^ (s & 15)) << 3) + (quad & 1) * 4) = w;
    }
  }
  __syncthreads();
#pragma unroll
  for (int i = 0; i < 16; ++i) {
    int idx = i * 256 + tid;
    *(float4*)(qp_g + (size_t)chunk * 32768 + idx * 8) = *(const float4*)(QP + idx * 8);
  }
}

// stepA: stage kpT (gl2lds) + vt hi/lo (via X), ctx = kpT@vt^T (2 passes),
// ctx hi/lo scattered to LDS (over dead KPT) then coalesced copy to ctx_g (aliases kpT_g chunk).
__global__ __launch_bounds__(256, 2)
void stepA(const unsigned short* __restrict__ kpT_g,
           const unsigned short* __restrict__ vth_g,
           const unsigned short* __restrict__ vtl_g,
           unsigned short* __restrict__ ctx_g)
{
  __shared__ __align__(16) char smem[81920];
  unsigned short* KPT = (unsigned short*)smem;            // 64 KB; later ctx hi@0, lo@16384 us
  unsigned short* X   = (unsigned short*)(smem + 65536);  // 16 KB
  const int tid = threadIdx.x, lane = tid & 63, wave = tid >> 6;
  const int fr = lane & 15, quad = lane >> 4;
  const int chunk = blockIdx.x;
  const int lofs = lane * 8;
  const unsigned short* kps = kpT_g + (size_t)chunk * 32768;
  const unsigned short* vhs = vth_g + (size_t)chunk * 8192;
  const unsigned short* vls = vtl_g + (size_t)chunk * 8192;
#pragma unroll
  for (int i = 0; i < 16; ++i) gl2lds16(kps + (wave*16+i)*512 + lofs, KPT + (wave*16+i)*512);
#pragma unroll
  for (int i = 0; i < 4; ++i)  gl2lds16(vhs + (wave*4+i)*512 + lofs, X + (wave*4+i)*512);
  __syncthreads();

  f32x4 acc_a[4][4];
#pragma unroll
  for (int i = 0; i < 4; ++i)
#pragma unroll
    for (int j = 0; j < 4; ++j) acc_a[i][j] = {0.f, 0.f, 0.f, 0.f};
#pragma unroll
  for (int ks = 0; ks < 4; ++ks) {
    int l = ks * 4 + quad;
    bf16x8 a[4];
#pragma unroll
    for (int mt = 0; mt < 4; ++mt) {
      int f = wave * 64 + mt * 16 + fr;
      a[mt] = *(const bf16x8*)(KPT + f * 128 + ((l ^ (f & 15)) << 3));
    }
#pragma unroll
    for (int nt = 0; nt < 4; ++nt) {
      int d = nt * 16 + fr;
      bf16x8 bh = *(const bf16x8*)(X + d * 128 + ((l ^ (d & 15)) << 3));
#pragma unroll
      for (int mt = 0; mt < 4; ++mt)
        acc_a[mt][nt] = __builtin_amdgcn_mfma_f32_16x16x32_bf16(a[mt], bh, acc_a[mt][nt], 0, 0, 0);
    }
  }
  __syncthreads();
#pragma unroll
  for (int i = 0; i < 4; ++i)  gl2lds16(vls + (wave*4+i)*512 + lofs, X + (wave*4+i)*512);
  __syncthreads();
#pragma unroll
  for (int ks = 0; ks < 4; ++ks) {
    int l = ks * 4 + quad;
    bf16x8 a[4];
#pragma unroll
    for (int mt = 0; mt < 4; ++mt) {
      int f = wave * 64 + mt * 16 + fr;
      a[mt] = *(const bf16x8*)(KPT + f * 128 + ((l ^ (f & 15)) << 3));
    }
#pragma unroll
    for (int nt = 0; nt < 4; ++nt) {
      int d = nt * 16 + fr;
      bf16x8 bl = *(const bf16x8*)(X + d * 128 + ((l ^ (d & 15)) << 3));
#pragma unroll
      for (int mt = 0; mt < 4; ++mt)
        acc_a[mt][nt] = __builtin_amdgcn_mfma_f32_16x16x32_bf16(a[mt], bl, acc_a[mt][nt], 0, 0, 0);
    }
  }
  __syncthreads();   // all KPT reads done before ctx overwrites it

  // ctx hi/lo -> LDS ([64 d][256 f] swz ^(d&15)), then coalesced copy out
#pragma unroll
  for (int mt = 0; mt < 4; ++mt)
#pragma unroll
    for (int nt = 0; nt < 4; ++nt) {
      int d = nt * 16 + fr;
      int g = wave * 8 + mt * 2 + (quad >> 1);
      float v0 = acc_a[mt][nt][0], v1 = acc_a[mt][nt][1];
      float v2 = acc_a[mt][nt][2], v3 = acc_a[mt][nt][3];
      unsigned short h0 = f2bf(v0), h1 = f2bf(v1), h2 = f2bf(v2), h3 = f2bf(v3);
      uint2 whi, wlo;
      whi.x = (unsigned)h0 | ((unsigned)h1 << 16);
      whi.y = (unsigned)h2 | ((unsigned)h3 << 16);
      wlo.x = pack2(v0 - bf2f(h0), v1 - bf2f(h1));
      wlo.y = pack2(v2 - bf2f(h2), v3 - bf2f(h3));
      int ad = d * 256 + ((g ^ (d & 15)) << 3) + (quad & 1) * 4;
      *(uint2*)(KPT + ad) = whi;
      *(uint2*)(KPT + 16384 + ad) = wlo;
    }
  __syncthreads();
#pragma unroll
  for (int i = 0; i < 16; ++i) {
    int idx = i * 256 + tid;
    *(float4*)(ctx_g + (size_t)chunk * 32768 + idx * 8) = *(const float4*)(KPT + idx * 8);
  }
}

// stepB: stage ctx (gl2lds, hi@0 lo@16384us), DI; out = (qp@ctx)*DI with qp B-frags
// direct from global. attn hi/lo stored [token][512].
__global__ __launch_bounds__(256, 2)
void stepB(const unsigned short* __restrict__ ctx_g,
           const unsigned short* __restrict__ qp_g,
           const float* __restrict__ di_g,
           unsigned short* __restrict__ attn_hi,
           unsigned short* __restrict__ attn_lo)
{
  __shared__ __align__(16) char smem[66048];
  unsigned short* CTX = (unsigned short*)smem;   // 64 KB
  float* DIL = (float*)(smem + 65536);           // [128]
  const int tid = threadIdx.x, lane = tid & 63, wave = tid >> 6;
  const int fr = lane & 15, quad = lane >> 4;
  const int chunk = blockIdx.x;
  const int b = chunk >> 8, h = (chunk >> 5) & 7, cc = chunk & 31;
  const int mbase = b * N_ + cc * CS_;
  const unsigned short* cs = ctx_g + (size_t)chunk * 32768;
  const unsigned short* qps = qp_g + (size_t)chunk * 32768;
#pragma unroll
  for (int i = 0; i < 16; ++i) gl2lds16(cs + (wave*16+i)*512 + lane*8, CTX + (wave*16+i)*512);
  if (tid < 128) DIL[tid] = di_g[(size_t)chunk * 128 + tid];
  __syncthreads();

  f32x4 acc2[4][2];
#pragma unroll
  for (int i = 0; i < 4; ++i) { acc2[i][0] = {0,0,0,0}; acc2[i][1] = {0,0,0,0}; }
#pragma unroll
  for (int ks = 0; ks < 8; ++ks) {
    int l = ks * 4 + quad;
    bf16x8 bq[2];
#pragma unroll
    for (int nt = 0; nt < 2; ++nt) {
      int s = wave * 32 + nt * 16 + fr;
      bq[nt] = *(const bf16x8*)(qps + s * 256 + ((l ^ (s & 15)) << 3));
    }
#pragma unroll
    for (int mt = 0; mt < 4; ++mt) {
      int d = mt * 16 + fr;
      int ad = d * 256 + ((l ^ (d & 15)) << 3);
      bf16x8 ah = *(const bf16x8*)(CTX + ad);
      bf16x8 al = *(const bf16x8*)(CTX + 16384 + ad);
#pragma unroll
      for (int nt = 0; nt < 2; ++nt) {
        acc2[mt][nt] = __builtin_amdgcn_mfma_f32_16x16x32_bf16(ah, bq[nt], acc2[mt][nt], 0, 0, 0);
        acc2[mt][nt] = __builtin_amdgcn_mfma_f32_16x16x32_bf16(al, bq[nt], acc2[mt][nt], 0, 0, 0);
      }
    }
  }
#pragma unroll
  for (int nt = 0; nt < 2; ++nt) {
    int s = wave * 32 + nt * 16 + fr;
    float di = DIL[s];
    size_t base = (size_t)(mbase + s) * 512 + h * DH_;
#pragma unroll
    for (int mt = 0; mt < 4; ++mt) {
      int d0 = mt * 16 + quad * 4;
      float o0 = acc2[mt][nt][0] * di, o1 = acc2[mt][nt][1] * di;
      float o2 = acc2[mt][nt][2] * di, o3 = acc2[mt][nt][3] * di;
      unsigned short h0 = f2bf(o0), h1 = f2bf(o1), h2 = f2bf(o2), h3 = f2bf(o3);
      uint2 whi, wlo;
      whi.x = (unsigned)h0 | ((unsigned)h1 << 16);
      whi.y = (unsigned)h2 | ((unsigned)h3 << 16);
      wlo.x = pack2(o0 - bf2f(h0), o1 - bf2f(h1));
      wlo.y = pack2(o2 - bf2f(h2), o3 - bf2f(h3));
      *(uint2*)(attn_hi + base + d0) = whi;
      *(uint2*)(attn_lo + base + d0) = wlo;
    }
  }
}

extern "C" void kernel_launch(void* const* d_in, const int* in_sizes, int n_in,
                              void* d_out, int out_size, void* d_ws, size_t ws_size,
                              hipStream_t stream)
{
  const float* x     = (const float*)d_in[0];
  const float* w_qkv = (const float*)d_in[1];
  const float* w_out = (const float*)d_in[2];
  const float* b_out = (const float*)d_in[3];
  const float* proj  = (const float*)d_in[4];
  float* out = (float*)d_out;

  // ws layout (209 MB):
  //  @0:          x_hi 16.8M | @16777216: x_lo 16.8M   -> attn_hi/attn_lo after feat_q
  //  @33554432:   wv_hi .5M | wv_lo | wout_hi | wout_lo
  //  @35651584:   wqp 2M | @37748736: wkp 2M
  //  @39845888:   vth 16.8M | @56623104: vtl 16.8M
  //  @73400320:   kpT 67M  (ctx aliases per-chunk: same 64KB block read->written by same block)
  //  @140509184:  qp 67M
  //  @207618048:  ksum 1M | @208666624: di 0.5M
  char* ws = (char*)d_ws;
  unsigned short* x_hi   = (unsigned short*)ws;
  unsigned short* x_lo   = (unsigned short*)(ws + 16777216);
  unsigned short* wv_hi  = (unsigned short*)(ws + 33554432);
  unsigned short* wv_lo  = (unsigned short*)(ws + 34078720);
  unsigned short* wout_hi= (unsigned short*)(ws + 34603008);
  unsigned short* wout_lo= (unsigned short*)(ws + 35127296);
  unsigned short* wqp    = (unsigned short*)(ws + 35651584);
  unsigned short* wkp    = (unsigned short*)(ws + 37748736);
  unsigned short* vth_g  = (unsigned short*)(ws + 39845888);
  unsigned short* vtl_g  = (unsigned short*)(ws + 56623104);
  unsigned short* kpT_g  = (unsigned short*)(ws + 73400320);
  unsigned short* ctx_g  = kpT_g;                       // per-chunk overlay (safe: same block)
  unsigned short* qp_g   = (unsigned short*)(ws + 140509184);
  float*          ksum_g = (float*)(ws + 207618048);
  float*          di_g   = (float*)(ws + 208666624);
  unsigned short* attn_hi = x_hi;                       // x splits dead after feat_q
  unsigned short* attn_lo = x_lo;

  // 1) splits: x (full), w_qkv v-rows, w_out
  split_kernel<<<dim3(M_*DIM_/4/256), 256, 0, stream>>>(x, x_hi, x_lo, M_*DIM_/4);
  split_kernel<<<dim3(DIM_*DIM_/4/256), 256, 0, stream>>>(w_qkv + (size_t)1024*DIM_,
                                                          wv_hi, wv_lo, DIM_*DIM_/4);
  split_kernel<<<dim3(DIM_*DIM_/4/256), 256, 0, stream>>>(w_out, wout_hi, wout_lo, DIM_*DIM_/4);
  // 2) combined feature weights (proj folded into Wq/Wk per head)
  wcomb_kernel<<<dim3(8, 2, 8), 256, 0, stream>>>(proj, w_qkv, wqp, wkp);
  // 3) v = x @ Wv^T (split) -> transposed hi/lo chunk layout
  mfma_gemm_nt<1,2><<<dim3(4, M_/128), 256, 0, stream>>>(
      x_hi, x_lo, wv_hi, wv_lo, nullptr, nullptr, DIM_, 0, vth_g, vtl_g);
  // 4) features: k' (kpT + ksum), then q' (qp + D)
  feat_k<<<dim3(NCHUNK_), 256, 0, stream>>>(x_hi, wkp, kpT_g, ksum_g);
  feat_q<<<dim3(NCHUNK_), 256, 0, stream>>>(x_hi, wqp, ksum_g, di_g, qp_g);
  // 5) stepA: ctx = kpT @ vt^T (ctx overlays kpT chunk)
  stepA<<<dim3(NCHUNK_), 256, 0, stream>>>(kpT_g, vth_g, vtl_g, ctx_g);
  // 6) stepB: attn = (qp @ ctx) * DI   (writes over x region)
  stepB<<<dim3(NCHUNK_), 256, 0, stream>>>(ctx_g, qp_g, di_g, attn_hi, attn_lo);
  // 7) out = attn @ w_out^T + b_out (split)
  mfma_gemm_nt<1,0><<<dim3(4, M_/128), 256, 0, stream>>>(
      attn_hi, attn_lo, wout_hi, wout_lo, out, b_out, DIM_, DIM_, nullptr, nullptr);
}